// Round 15
// baseline (1600.432 us; speedup 1.0000x reference)
//
#include <hip/hip_runtime.h>
#include <hip/hip_bf16.h>

// ---------------- constants ----------------
constexpr int CB   = 2;
constexpr int CS   = 2048;
constexpr int CH   = 2048;
constexpr int CNH  = 16;
constexpr int CHD  = 128;
constexpr int CE   = 8;
constexpr int CI   = 2048;
constexpr int CT   = CB * CS;
constexpr int CQK  = 4096;   // q|k row stride

typedef __attribute__((ext_vector_type(8))) short short8;
typedef __attribute__((ext_vector_type(4))) float float4v;
typedef __attribute__((ext_vector_type(4))) unsigned short ushort4v;
typedef unsigned int uint32;

__device__ __forceinline__ float bf2f(unsigned short u) {
    union { unsigned int i; float f; } x; x.i = ((unsigned int)u) << 16; return x.f;
}
__device__ __forceinline__ unsigned short f2bf(float f) {
    union { float f; unsigned int i; } x; x.f = f;
    unsigned int r = x.i + 0x7fffu + ((x.i >> 16) & 1u);
    return (unsigned short)(r >> 16);
}
__device__ __forceinline__ uint32 packpair(uint32 r0, uint32 r1) {
    return __builtin_amdgcn_perm(r1, r0, 0x07060302u);
}
__device__ __forceinline__ uint32 rnebits(float f) {
    uint32 u = __float_as_uint(f);
    return u + 0x7fffu + ((u >> 16) & 1u);
}
__device__ __forceinline__ void split2(float f0, float f1, uint32& h, uint32& l) {
    uint32 r0 = rnebits(f0), r1 = rnebits(f1);
    h = packpair(r0, r1);
    float d0 = f0 - __uint_as_float(r0 & 0xffff0000u);
    float d1 = f1 - __uint_as_float(r1 & 0xffff0000u);
    l = packpair(rnebits(d0), rnebits(d1));
}
__device__ __forceinline__ void rne16_store(const float* fv, unsigned short* dst) {
    uint32 h[8];
    #pragma unroll
    for (int p = 0; p < 8; p++) h[p] = packpair(rnebits(fv[2 * p]), rnebits(fv[2 * p + 1]));
    ((uint4*)dst)[0] = make_uint4(h[0], h[1], h[2], h[3]);
    ((uint4*)dst)[1] = make_uint4(h[4], h[5], h[6], h[7]);
}
// async global->LDS: 16B per lane, lds dest = wave-uniform base + lane*16
__device__ __forceinline__ void gl16(const void* g, void* l) {
    __builtin_amdgcn_global_load_lds(
        (const __attribute__((address_space(1))) void*)g,
        (__attribute__((address_space(3))) void*)l, 16, 0, 0);
}

// ---------------- RMSNorm (hi/lo split out) ----------
__global__ __launch_bounds__(256) void rmsnorm_k(const float* __restrict__ x,
                                                 const float* __restrict__ w,
                                                 unsigned short* __restrict__ o1,
                                                 unsigned short* __restrict__ o2) {
    const int row = blockIdx.x;
    const float* xr = x + (size_t)row * CH;
    const int base = threadIdx.x * 8;
    float4 v0 = *(const float4*)(xr + base);
    float4 v1 = *(const float4*)(xr + base + 4);
    float ss = v0.x*v0.x + v0.y*v0.y + v0.z*v0.z + v0.w*v0.w
             + v1.x*v1.x + v1.y*v1.y + v1.z*v1.z + v1.w*v1.w;
    #pragma unroll
    for (int o = 1; o < 64; o <<= 1) ss += __shfl_xor(ss, o);
    __shared__ float ps[4];
    if ((threadIdx.x & 63) == 0) ps[threadIdx.x >> 6] = ss;
    __syncthreads();
    const float scale = rsqrtf((ps[0] + ps[1] + ps[2] + ps[3]) / (float)CH + 1e-5f);
    float4 w0 = *(const float4*)(w + base);
    float4 w1 = *(const float4*)(w + base + 4);
    float r[8] = {v0.x * scale * w0.x, v0.y * scale * w0.y, v0.z * scale * w0.z, v0.w * scale * w0.w,
                  v1.x * scale * w1.x, v1.y * scale * w1.y, v1.z * scale * w1.z, v1.w * scale * w1.w};
    uint32 h[4], l[4];
    #pragma unroll
    for (int p = 0; p < 4; p++) split2(r[2 * p], r[2 * p + 1], h[p], l[p]);
    *(uint4*)(o1 + (size_t)row * CH + base) = make_uint4(h[0], h[1], h[2], h[3]);
    *(uint4*)(o2 + (size_t)row * CH + base) = make_uint4(l[0], l[1], l[2], l[3]);
}

// ---------------- fused RMSNorm2 + router ----------------
__global__ __launch_bounds__(256) void rmsrouter_k(const float* __restrict__ x,
                                                   const float* __restrict__ w,
                                                   const float* __restrict__ rw,
                                                   unsigned short* __restrict__ h2,
                                                   int* __restrict__ cnt,
                                                   int* __restrict__ tok,
                                                   float* __restrict__ gate) {
    const int row = blockIdx.x;
    const float* xr = x + (size_t)row * CH;
    const int base = threadIdx.x * 8;
    float4 v0 = *(const float4*)(xr + base);
    float4 v1 = *(const float4*)(xr + base + 4);
    float ss = v0.x*v0.x + v0.y*v0.y + v0.z*v0.z + v0.w*v0.w
             + v1.x*v1.x + v1.y*v1.y + v1.z*v1.z + v1.w*v1.w;
    #pragma unroll
    for (int o = 1; o < 64; o <<= 1) ss += __shfl_xor(ss, o);
    __shared__ float ps[4];
    __shared__ double dacc[4][8];
    const int wave = threadIdx.x >> 6, lane = threadIdx.x & 63;
    if (lane == 0) ps[wave] = ss;
    __syncthreads();
    const float scale = rsqrtf((ps[0] + ps[1] + ps[2] + ps[3]) / (float)CH + 1e-5f);
    float4 w0 = *(const float4*)(w + base);
    float4 w1 = *(const float4*)(w + base + 4);
    float r[8] = {v0.x * scale * w0.x, v0.y * scale * w0.y, v0.z * scale * w0.z, v0.w * scale * w0.w,
                  v1.x * scale * w1.x, v1.y * scale * w1.y, v1.z * scale * w1.z, v1.w * scale * w1.w};
    rne16_store(r, h2 + (size_t)row * CH + base);
    const float vv[8] = {v0.x, v0.y, v0.z, v0.w, v1.x, v1.y, v1.z, v1.w};
    const float ww[8] = {w0.x, w0.y, w0.z, w0.w, w1.x, w1.y, w1.z, w1.w};
    double acc[8] = {0, 0, 0, 0, 0, 0, 0, 0};
    #pragma unroll
    for (int jj = 0; jj < 8; jj++) {
        const double xn = (double)vv[jj] * (double)ww[jj];
        const float* rr = rw + (size_t)(base + jj) * CE;
        #pragma unroll
        for (int e = 0; e < 8; e++) acc[e] += xn * (double)rr[e];
    }
    #pragma unroll
    for (int e = 0; e < 8; e++) {
        #pragma unroll
        for (int o = 1; o < 64; o <<= 1) acc[e] += __shfl_xor(acc[e], o);
    }
    if (lane == 0) {
        #pragma unroll
        for (int e = 0; e < 8; e++) dacc[wave][e] = acc[e];
    }
    __syncthreads();
    if (threadIdx.x == 0) {
        double a[8];
        #pragma unroll
        for (int e = 0; e < 8; e++) a[e] = dacc[0][e] + dacc[1][e] + dacc[2][e] + dacc[3][e];
        int e0 = 0;
        #pragma unroll
        for (int e = 1; e < 8; e++) if (a[e] > a[e0]) e0 = e;
        int e1 = (e0 == 0) ? 1 : 0;
        #pragma unroll
        for (int e = 0; e < 8; e++) if (e != e0 && a[e] > a[e1]) e1 = e;
        const double dl = (double)scale * (a[e1] - a[e0]);   // <= 0
        const double p1r = exp(dl);
        const float g0 = (float)(1.0 / (1.0 + p1r));
        const float g1 = (float)(p1r / (1.0 + p1r));
        int pos0 = atomicAdd(&cnt[e0], 1);
        tok[e0 * 4096 + pos0] = row; gate[e0 * 4096 + pos0] = g0;
        int pos1 = atomicAdd(&cnt[e1], 1);
        tok[e1 * 4096 + pos1] = row; gate[e1 * 4096 + pos1] = g1;
    }
}

// ---------------- RoPE table ----
__global__ void rope_tab_k(float2* __restrict__ tab) {
    int i = blockIdx.x * 256 + threadIdx.x;
    int p = i >> 6, j = i & 63;
    double inv = pow(10000.0, -(double)j / 64.0);
    float invf = (float)inv;
    float angf = (float)p * invf;
    double da = (double)angf;
    tab[i] = make_float2((float)cos(da), (float)sin(da));
}

// ---------------- weight transpose+convert: src[K][N] f32 -> dst[N][K] bf16 ----
template<int NMAT>
__global__ __launch_bounds__(256) void conv_k(const float* __restrict__ S0,
                                              const float* __restrict__ S1,
                                              unsigned short* __restrict__ D) {
    __shared__ float t[64][65];
    const int n0 = blockIdx.x * 64, k0 = blockIdx.y * 64, e = blockIdx.z;
    const size_t esrc = (size_t)e * 2048 * 2048;
    const int cc = threadIdx.x & 63, r4 = threadIdx.x >> 6;
    const int nl = threadIdx.x >> 2, q = threadIdx.x & 3;
    #pragma unroll
    for (int s = 0; s < NMAT; s++) {
        const float* S = s ? S1 : S0;
        __syncthreads();
        #pragma unroll
        for (int j = 0; j < 16; j++) {
            const int row = j * 4 + r4;
            t[cc][row] = S[esrc + (size_t)(k0 + row) * 2048 + n0 + cc];
        }
        __syncthreads();
        const int orow = (NMAT == 2) ? (2 * (n0 + nl) + s) : (n0 + nl);
        unsigned short* dp = D + (size_t)e * (NMAT * 2048) * 2048 + (size_t)orow * 2048 + k0 + q * 16;
        float fv[16];
        #pragma unroll
        for (int j = 0; j < 16; j++) fv[j] = t[nl][q * 16 + j];
        rne16_store(fv, dp);
    }
}

// ---------------- weight transpose + hi/lo SPLIT convert --------------------
// NMAT==3 (q,k,v): z<2 columns get rope-interleaved head-dim: d<64 -> 2d, d>=64 -> 2(d-64)+1
template<int NMAT>
__global__ __launch_bounds__(256) void convs_k(const float* __restrict__ S0,
                                               const float* __restrict__ S1,
                                               const float* __restrict__ S2,
                                               unsigned short* __restrict__ Dh,
                                               unsigned short* __restrict__ Dl) {
    __shared__ float t[64][65];
    const int n0 = blockIdx.x * 64, k0 = blockIdx.y * 64, z = blockIdx.z;
    const float* S = S0;
    if (NMAT == 3) S = (z == 0) ? S0 : ((z == 1) ? S1 : S2);
    const int cc = threadIdx.x & 63, r4 = threadIdx.x >> 6;
    #pragma unroll
    for (int j = 0; j < 16; j++) {
        const int row = j * 4 + r4;
        t[cc][row] = S[(size_t)(k0 + row) * 2048 + n0 + cc];
    }
    __syncthreads();
    const int nl = threadIdx.x >> 2, q = threadIdx.x & 3;
    float fv[16];
    #pragma unroll
    for (int j = 0; j < 16; j++) fv[j] = t[nl][q * 16 + j];
    uint32 h[8], l[8];
    #pragma unroll
    for (int p = 0; p < 8; p++) split2(fv[2 * p], fv[2 * p + 1], h[p], l[p]);
    int orow;
    const int gcol = n0 + nl;
    if (NMAT == 3 && z < 2) {
        const int head = gcol >> 7, dd = gcol & 127;
        const int nd = (dd < 64) ? (2 * dd) : (2 * (dd - 64) + 1);
        orow = z * 2048 + head * 128 + nd;
    } else {
        orow = z * 2048 + gcol;
    }
    const size_t off = (size_t)orow * 2048 + k0 + q * 16;
    ((uint4*)(Dh + off))[0] = make_uint4(h[0], h[1], h[2], h[3]);
    ((uint4*)(Dh + off))[1] = make_uint4(h[4], h[5], h[6], h[7]);
    ((uint4*)(Dl + off))[0] = make_uint4(l[0], l[1], l[2], l[3]);
    ((uint4*)(Dl + off))[1] = make_uint4(l[4], l[5], l[6], l[7]);
}

// ---------------- precise split-bf16 GEMM, gl16 + LDS double-buffer -----------
// MODE 0 (QKV): q,k cols (nt<32) get fused ROPE then split-store (stride 4096);
//               v cols (nt>=32) -> Vh/Vl transposed [vcol][token]
// MODE 1 (O-proj): C f32 + resid, dual-store
template<int MODE>
__global__ __launch_bounds__(256) void sgemm_k(
    const unsigned short* __restrict__ Ahg, const unsigned short* __restrict__ Alg, int lda,
    const unsigned short* __restrict__ Bhg, const unsigned short* __restrict__ Blg, int K,
    unsigned short* __restrict__ Ch, unsigned short* __restrict__ Cl,
    float* __restrict__ Cf, int ldc,
    const float* __restrict__ resid, float* __restrict__ C2,
    unsigned short* __restrict__ Vh, unsigned short* __restrict__ Vl,
    const int* __restrict__ posids, const float2* __restrict__ rtab) {
    __shared__ unsigned short SS[2][4][128 * 32];
    const int mt = blockIdx.x, nt = blockIdx.y, tid = threadIdx.x;
    const int m0 = mt * 128;
    const int wave = tid >> 6, lane = tid & 63;
    const int lr = lane & 15, lg = lane >> 4;
    const int wr = (tid >> 7) & 1, wc = (tid >> 6) & 1;
    const int sr = lane >> 2;
    const int sc = (lane & 3) * 8;
    const int r0 = wave * 32;
    const int lofs = r0 * 32;
    const unsigned short* gAh = Ahg + (size_t)(m0 + r0 + sr) * lda + sc;
    const unsigned short* gAl = Alg + (size_t)(m0 + r0 + sr) * lda + sc;
    const unsigned short* gBh = Bhg + (size_t)(nt * 128 + r0 + sr) * K + sc;
    const unsigned short* gBl = Blg + (size_t)(nt * 128 + r0 + sr) * K + sc;
    const size_t rstepA = (size_t)16 * lda, rstepB = (size_t)16 * K;

    float4v acc[4][4];
    #pragma unroll
    for (int m = 0; m < 4; m++)
        #pragma unroll
        for (int n = 0; n < 4; n++) acc[m][n] = (float4v){0.f, 0.f, 0.f, 0.f};

    gl16(gAh, &SS[0][0][lofs]);           gl16(gAh + rstepA, &SS[0][0][lofs + 512]);
    gl16(gAl, &SS[0][1][lofs]);           gl16(gAl + rstepA, &SS[0][1][lofs + 512]);
    gl16(gBh, &SS[0][2][lofs]);           gl16(gBh + rstepB, &SS[0][2][lofs + 512]);
    gl16(gBl, &SS[0][3][lofs]);           gl16(gBl + rstepB, &SS[0][3][lofs + 512]);
    __syncthreads();

    int cur = 0;
    for (int k0 = 0; k0 < K; k0 += 32) {
        if (k0 + 32 < K) {
            const int nb = cur ^ 1;
            const int kn = k0 + 32;
            gl16(gAh + kn, &SS[nb][0][lofs]);          gl16(gAh + kn + rstepA, &SS[nb][0][lofs + 512]);
            gl16(gAl + kn, &SS[nb][1][lofs]);          gl16(gAl + kn + rstepA, &SS[nb][1][lofs + 512]);
            gl16(gBh + kn, &SS[nb][2][lofs]);          gl16(gBh + kn + rstepB, &SS[nb][2][lofs + 512]);
            gl16(gBl + kn, &SS[nb][3][lofs]);          gl16(gBl + kn + rstepB, &SS[nb][3][lofs + 512]);
        }
        const unsigned short* PAh = SS[cur][0];
        const unsigned short* PAl = SS[cur][1];
        const unsigned short* PBh = SS[cur][2];
        const unsigned short* PBl = SS[cur][3];
        short8 fah[4], fal[4], fbh[4], fbl[4];
        #pragma unroll
        for (int m = 0; m < 4; m++) {
            fah[m] = *(const short8*)(PAh + (wr * 64 + m * 16 + lr) * 32 + lg * 8);
            fal[m] = *(const short8*)(PAl + (wr * 64 + m * 16 + lr) * 32 + lg * 8);
        }
        #pragma unroll
        for (int n = 0; n < 4; n++) {
            fbh[n] = *(const short8*)(PBh + (wc * 64 + n * 16 + lr) * 32 + lg * 8);
            fbl[n] = *(const short8*)(PBl + (wc * 64 + n * 16 + lr) * 32 + lg * 8);
        }
        #pragma unroll
        for (int n = 0; n < 4; n++)
            #pragma unroll
            for (int m = 0; m < 4; m++) {
                acc[m][n] = __builtin_amdgcn_mfma_f32_16x16x32_bf16(fal[m], fbh[n], acc[m][n], 0, 0, 0);
                acc[m][n] = __builtin_amdgcn_mfma_f32_16x16x32_bf16(fah[m], fbl[n], acc[m][n], 0, 0, 0);
                acc[m][n] = __builtin_amdgcn_mfma_f32_16x16x32_bf16(fah[m], fbh[n], acc[m][n], 0, 0, 0);
            }
        __syncthreads();
        cur ^= 1;
    }
    if (MODE == 0 && nt >= 32) {
        // V columns: transposed packed store vT[vcol][token]
        #pragma unroll
        for (int m = 0; m < 4; m++) {
            const int rb = wr * 64 + m * 16 + lg * 4;
            #pragma unroll
            for (int n = 0; n < 4; n++) {
                const int vcol = nt * 128 + wc * 64 + n * 16 + lr - 4096;
                ushort4v wh4, wl4;
                #pragma unroll
                for (int r = 0; r < 4; r++) {
                    const float v = acc[m][n][r];
                    uint32 rr = rnebits(v);
                    wh4[r] = (unsigned short)(rr >> 16);
                    wl4[r] = f2bf(v - __uint_as_float(rr & 0xffff0000u));
                }
                *(ushort4v*)(Vh + (size_t)vcol * (size_t)CT + (m0 + rb)) = wh4;
                *(ushort4v*)(Vl + (size_t)vcol * (size_t)CT + (m0 + rb)) = wl4;
            }
        }
        return;
    }
    if (MODE == 0) {
        // q/k columns: fused rope (interleaved pairs at adjacent lanes) + split store
        #pragma unroll
        for (int m = 0; m < 4; m++) {
            const int rb = wr * 64 + m * 16 + lg * 4;
            #pragma unroll
            for (int n = 0; n < 4; n++) {
                const int ccol = nt * 128 + wc * 64 + n * 16 + lr;
                const int j = (wc * 64 + n * 16 + lr) >> 1;   // head-local pair index
                #pragma unroll
                for (int r = 0; r < 4; r++) {
                    const int row = m0 + rb + r;
                    const float v = acc[m][n][r];
                    const float partner = __shfl_xor(v, 1);
                    const float2 cs = rtab[(size_t)posids[row] * 64 + j];
                    const float y = (lr & 1) ? (v * cs.x + partner * cs.y)
                                             : (v * cs.x - partner * cs.y);
                    const size_t idx = (size_t)row * ldc + ccol;
                    uint32 rr = rnebits(y);
                    Ch[idx] = (unsigned short)(rr >> 16);
                    Cl[idx] = f2bf(y - __uint_as_float(rr & 0xffff0000u));
                }
            }
        }
        return;
    }
    #pragma unroll
    for (int m = 0; m < 4; m++) {
        const int rb = wr * 64 + m * 16 + lg * 4;
        #pragma unroll
        for (int n = 0; n < 4; n++) {
            const int ccol = nt * 128 + wc * 64 + n * 16 + lr;
            #pragma unroll
            for (int r = 0; r < 4; r++) {
                const size_t idx = (size_t)(m0 + rb + r) * ldc + ccol;
                const float v = acc[m][n][r] + resid[idx];
                Cf[idx] = v;
                C2[idx] = v;
            }
        }
    }
}

// ---------------- MoE GEMM: 128x256 block, 4 waves x (128x64), gl16 dbuf ------
// MODE 2: up (N=2*CI interleaved w1/w3, SwiGLU -> bf16 H). MODE 3: down (atomicAdd).
template<int MODE>
__global__ __launch_bounds__(256) void gemm_k(
    const unsigned short* __restrict__ A, int lda,
    const unsigned short* __restrict__ Bt, int K, int Ne,
    void* __restrict__ Cp, int ldc,
    const int* __restrict__ cnt, const int* __restrict__ tokl,
    const float* __restrict__ gatel, const int* __restrict__ pb) {
    __shared__ unsigned short AS[2][128 * 32];
    __shared__ unsigned short BS[2][256 * 32];
    const int nt = blockIdx.x, mt = blockIdx.y, e = blockIdx.z;
    const int m0 = mt * 128;
    const int c = cnt[e];
    if (m0 >= c) return;
    const int valid = (c - m0 < 128) ? (c - m0) : 128;
    const int tid = threadIdx.x;
    const int wave = tid >> 6, lane = tid & 63;
    const int lr = lane & 15, lg = lane >> 4;
    const size_t eoff = (size_t)e * Ne * K;

    // A staging: 512 chunks (row*4+q), 2 issues/thread
    const unsigned short* gA[2];
    int abase[2];
    #pragma unroll
    for (int i = 0; i < 2; i++) {
        const int chunk = wave * 64 + i * 256 + lane;
        const int arow = chunk >> 2, aq = chunk & 3;
        size_t gr;
        if (MODE == 2) {
            const int idx = m0 + (arow < valid ? arow : valid - 1);
            gr = (size_t)tokl[e * 4096 + idx];
        } else {
            const int x = m0 + arow;
            gr = (size_t)(pb[e] + (x < c ? x : c - 1));
        }
        gA[i] = A + gr * (size_t)lda + aq * 8;
        abase[i] = (wave * 64 + i * 256) * 8;
    }
    // B staging: 1024 chunks (col*4+q), 4 issues/thread
    const unsigned short* gB[4];
    int bbase[4];
    #pragma unroll
    for (int i = 0; i < 4; i++) {
        const int chunk = wave * 64 + i * 256 + lane;
        const int bcol = chunk >> 2, bq = chunk & 3;
        gB[i] = Bt + eoff + (size_t)(nt * 256 + bcol) * K + bq * 8;
        bbase[i] = (wave * 64 + i * 256) * 8;
    }

    float4v acc[8][4];
    #pragma unroll
    for (int m = 0; m < 8; m++)
        #pragma unroll
        for (int n = 0; n < 4; n++) acc[m][n] = (float4v){0.f, 0.f, 0.f, 0.f};

    #pragma unroll
    for (int i = 0; i < 2; i++) gl16(gA[i], &AS[0][abase[i]]);
    #pragma unroll
    for (int i = 0; i < 4; i++) gl16(gB[i], &BS[0][bbase[i]]);
    __syncthreads();

    int cur = 0;
    for (int k0 = 0; k0 < K; k0 += 32) {
        if (k0 + 32 < K) {
            const int nb = cur ^ 1;
            const int kn = k0 + 32;
            #pragma unroll
            for (int i = 0; i < 2; i++) gl16(gA[i] + kn, &AS[nb][abase[i]]);
            #pragma unroll
            for (int i = 0; i < 4; i++) gl16(gB[i] + kn, &BS[nb][bbase[i]]);
        }
        const unsigned short* PA = AS[cur];
        const unsigned short* PB = BS[cur];
        short8 bf[4];
        #pragma unroll
        for (int n = 0; n < 4; n++)
            bf[n] = *(const short8*)(PB + (wave * 64 + n * 16 + lr) * 32 + lg * 8);
        #pragma unroll
        for (int m = 0; m < 8; m++) {
            short8 af = *(const short8*)(PA + (m * 16 + lr) * 32 + lg * 8);
            #pragma unroll
            for (int n = 0; n < 4; n++)
                acc[m][n] = __builtin_amdgcn_mfma_f32_16x16x32_bf16(af, bf[n], acc[m][n], 0, 0, 0);
        }
        __syncthreads();
        cur ^= 1;
    }

    #pragma unroll
    for (int m = 0; m < 8; m++) {
        const int rb = m * 16 + lg * 4;
        #pragma unroll
        for (int n = 0; n < 4; n++) {
            const int col = nt * 256 + wave * 64 + n * 16 + lr;
            #pragma unroll
            for (int r = 0; r < 4; r++) {
                const int row = rb + r;
                const float v = acc[m][n][r];
                if (MODE == 2) {
                    const float other = __shfl_xor(v, 1);
                    if (!(lr & 1) && row < valid) {
                        const float g1 = v, g3 = other;
                        const float hsw = (g1 / (1.f + __expf(-g1))) * g3;
                        ((unsigned short*)Cp)[(size_t)(pb[e] + m0 + row) * ldc + (col >> 1)] = f2bf(hsw);
                    }
                } else {
                    if (row < valid) {
                        const int t = tokl[e * 4096 + m0 + row];
                        const float g = gatel[e * 4096 + m0 + row];
                        atomicAdd(((float*)Cp) + (size_t)t * ldc + col, v * g);
                    }
                }
            }
        }
    }
}

// ---------------- flash attention: XCD-pinned, single-barrier dbuf, gl16 V ----
__global__ __launch_bounds__(256) void attn_k(const unsigned short* __restrict__ qkh,
                                              const unsigned short* __restrict__ qkl,
                                              const unsigned short* __restrict__ vth,
                                              const unsigned short* __restrict__ vtl,
                                              unsigned short* __restrict__ ch,
                                              unsigned short* __restrict__ cl) {
    __shared__ unsigned short Kb[2][2][32][136];
    __shared__ unsigned short Vb[2][2][128 * 32];
    const int bid = blockIdx.x;          // 1024 blocks
    const int xcd = bid & 7, jj = bid >> 3;
    const int bh  = xcd * 4 + (jj >> 5);
    const int qb  = 31 - (jj & 31);
    const int h   = bh & 15, b = bh >> 4;
    const int tid = threadIdx.x;
    const int wave = tid >> 6, lane = tid & 63, lr = lane & 15, lg = lane >> 4;
    const size_t tb = (size_t)b * CS;
    const int q0 = qb * 64 + wave * 16;

    short8 qfh[4], qfl[4];
    {
        const size_t off = (tb + q0 + lr) * CQK + h * CHD;
        #pragma unroll
        for (int c = 0; c < 4; c++) {
            qfh[c] = *(const short8*)(qkh + off + c * 32 + lg * 8);
            qfl[c] = *(const short8*)(qkl + off + c * 32 + lg * 8);
        }
    }
    float4v o[8];
    #pragma unroll
    for (int d = 0; d < 8; d++) o[d] = (float4v){0.f, 0.f, 0.f, 0.f};
    float m = -1e30f, l = 0.f;
    const float scl = 0.08838834764831845f;
    const int ntiles = 2 * (qb + 1);
    const int kk = tid >> 3, slot = tid & 7;

    short8 kh0, kh1, kl0, kl1;
    const size_t vrow = (size_t)(h * 128 + wave * 32 + (lane >> 2));
    const unsigned short* gV0 = vth + vrow * (size_t)CT + tb + (lane & 3) * 8;
    const unsigned short* gV1 = vtl + vrow * (size_t)CT + tb + (lane & 3) * 8;

    #define LOADK(KV0) { \
        const size_t koff = (tb + (KV0) + kk) * CQK + CH + h * CHD + slot * 16; \
        kh0 = *(const short8*)(qkh + koff);     kh1 = *(const short8*)(qkh + koff + 8); \
        kl0 = *(const short8*)(qkl + koff);     kl1 = *(const short8*)(qkl + koff + 8); }
    #define WRITEK(BUF) { \
        *(short8*)(&Kb[BUF][0][kk][slot * 16])     = kh0; \
        *(short8*)(&Kb[BUF][0][kk][slot * 16 + 8]) = kh1; \
        *(short8*)(&Kb[BUF][1][kk][slot * 16])     = kl0; \
        *(short8*)(&Kb[BUF][1][kk][slot * 16 + 8]) = kl1; }
    #define ISSUEV(BUF, KV0) { \
        gl16(gV0 + (KV0), &Vb[BUF][0][wave * 32 * 32]); \
        gl16(gV0 + (KV0) + (size_t)16 * CT, &Vb[BUF][0][wave * 32 * 32 + 512]); \
        gl16(gV1 + (KV0), &Vb[BUF][1][wave * 32 * 32]); \
        gl16(gV1 + (KV0) + (size_t)16 * CT, &Vb[BUF][1][wave * 32 * 32 + 512]); }

    LOADK(0);
    WRITEK(0);
    ISSUEV(0, 0);
    LOADK(32);
    __syncthreads();

    int cur = 0;
    for (int kt = 0; kt < ntiles; ++kt) {
        const int kv0 = kt * 32;
        if (kt + 1 < ntiles) {
            WRITEK(cur ^ 1);
            ISSUEV(cur ^ 1, kv0 + 32);
        }
        if (kt + 2 < ntiles) LOADK(kv0 + 64);

        const unsigned short* KH = &Kb[cur][0][0][0];
        const unsigned short* KL = &Kb[cur][1][0][0];
        const unsigned short* VH = Vb[cur][0];
        const unsigned short* VL = Vb[cur][1];

        float4v st0 = (float4v){0.f,0.f,0.f,0.f}, st1 = st0;
        #pragma unroll
        for (int c = 0; c < 4; c++) {
            short8 kah = *(const short8*)(KH + lr * 136 + c * 32 + lg * 8);
            short8 kal = *(const short8*)(KL + lr * 136 + c * 32 + lg * 8);
            short8 kbh = *(const short8*)(KH + (16 + lr) * 136 + c * 32 + lg * 8);
            short8 kbl = *(const short8*)(KL + (16 + lr) * 136 + c * 32 + lg * 8);
            st0 = __builtin_amdgcn_mfma_f32_16x16x32_bf16(kal, qfh[c], st0, 0, 0, 0);
            st0 = __builtin_amdgcn_mfma_f32_16x16x32_bf16(kah, qfl[c], st0, 0, 0, 0);
            st0 = __builtin_amdgcn_mfma_f32_16x16x32_bf16(kah, qfh[c], st0, 0, 0, 0);
            st1 = __builtin_amdgcn_mfma_f32_16x16x32_bf16(kbl, qfh[c], st1, 0, 0, 0);
            st1 = __builtin_amdgcn_mfma_f32_16x16x32_bf16(kbh, qfl[c], st1, 0, 0, 0);
            st1 = __builtin_amdgcn_mfma_f32_16x16x32_bf16(kbh, qfh[c], st1, 0, 0, 0);
        }
        float pv[8]; float pmax = -1e30f;
        const int qg = q0 + lr;
        #pragma unroll
        for (int f = 0; f < 2; f++) {
            #pragma unroll
            for (int r = 0; r < 4; r++) {
                const int kg = kv0 + f * 16 + lg * 4 + r;
                const float s = (kg <= qg) ? ((f ? st1[r] : st0[r]) * scl) : -1e30f;
                pv[f * 4 + r] = s;
                pmax = fmaxf(pmax, s);
            }
        }
        pmax = fmaxf(pmax, __shfl_xor(pmax, 16));
        pmax = fmaxf(pmax, __shfl_xor(pmax, 32));
        if (!__all(pmax <= m)) {
            const float mnew = fmaxf(m, pmax);
            const float alpha = __expf(m - mnew);
            l *= alpha;
            #pragma unroll
            for (int d = 0; d < 8; d++) o[d] *= alpha;
            m = mnew;
        }
        float sum = 0.f;
        #pragma unroll
        for (int i = 0; i < 8; i++) { const float p = __expf(pv[i] - m); pv[i] = p; sum += p; }
        sum += __shfl_xor(sum, 16);
        sum += __shfl_xor(sum, 32);
        l += sum;
        short8 pfh, pfl;
        unsigned short* pfhp = (unsigned short*)&pfh;
        unsigned short* pflp = (unsigned short*)&pfl;
        #pragma unroll
        for (int j = 0; j < 8; j++) {
            const int srcl = (((lg & 1) * 2 + (j >> 2)) << 4) | lr;
            const float a0 = __shfl(pv[j & 3], srcl);
            const float a1 = __shfl(pv[4 + (j & 3)], srcl);
            const float sel = (lg >= 2) ? a1 : a0;
            uint32 r = rnebits(sel);
            pfhp[j] = (unsigned short)(r >> 16);
            float d = sel - __uint_as_float(r & 0xffff0000u);
            pflp[j] = (unsigned short)(rnebits(d) >> 16);
        }
        #pragma unroll
        for (int dt = 0; dt < 8; dt++) {
            short8 vh = *(const short8*)(VH + (dt * 16 + lr) * 32 + lg * 8);
            short8 vl = *(const short8*)(VL + (dt * 16 + lr) * 32 + lg * 8);
            o[dt] = __builtin_amdgcn_mfma_f32_16x16x32_bf16(vl, pfh, o[dt], 0, 0, 0);
            o[dt] = __builtin_amdgcn_mfma_f32_16x16x32_bf16(vh, pfl, o[dt], 0, 0, 0);
            o[dt] = __builtin_amdgcn_mfma_f32_16x16x32_bf16(vh, pfh, o[dt], 0, 0, 0);
        }
        __syncthreads();
        cur ^= 1;
    }
    #undef LOADK
    #undef WRITEK
    #undef ISSUEV
    const float inv = 1.f / l;
    const size_t coff = (tb + q0 + lr) * CH + h * CHD + lg * 4;
    #pragma unroll
    for (int dt = 0; dt < 8; dt++) {
        ushort4v wh, wl;
        #pragma unroll
        for (int r = 0; r < 4; r++) {
            const float v = o[dt][r] * inv;
            uint32 rr = rnebits(v);
            wh[r] = (unsigned short)(rr >> 16);
            wl[r] = f2bf(v - __uint_as_float(rr & 0xffff0000u));
        }
        *(ushort4v*)(ch + coff + dt * 16) = wh;
        *(ushort4v*)(cl + coff + dt * 16) = wl;
    }
}

__global__ void prefix_k(const int* __restrict__ cnt, int* __restrict__ pb) {
    if (threadIdx.x == 0 && blockIdx.x == 0) {
        int s = 0;
        for (int e = 0; e < CE; e++) { pb[e] = s; s += cnt[e]; }
    }
}

// ---------------- launch ----------------
extern "C" void kernel_launch(void* const* d_in, const int* in_sizes, int n_in,
                              void* d_out, int out_size, void* d_ws, size_t ws_size,
                              hipStream_t stream) {
    (void)in_sizes; (void)n_in; (void)out_size; (void)ws_size;
    const float* hidden = (const float*)d_in[0];
    const int*   posids = (const int*)d_in[1];
    const float* rms1w  = (const float*)d_in[2];
    const float* rms2w  = (const float*)d_in[3];
    const float* qw     = (const float*)d_in[4];
    const float* kw     = (const float*)d_in[5];
    const float* vw     = (const float*)d_in[6];
    const float* ow     = (const float*)d_in[7];
    const float* rw     = (const float*)d_in[8];
    const float* w1     = (const float*)d_in[9];
    const float* w2     = (const float*)d_in[10];
    const float* w3     = (const float*)d_in[11];
    float* out = (float*)d_out;

    char* ws = (char*)d_ws;
    unsigned short* h1h = (unsigned short*)ws;
    unsigned short* h1l = (unsigned short*)(ws + 16777216);
    unsigned short* woh = (unsigned short*)ws;
    unsigned short* wol = (unsigned short*)(ws + 8388608);
    unsigned short* h2  = (unsigned short*)ws;
    int*   tok  = (int*)(ws + 16777216);
    float* gate = (float*)(ws + 16777216 + 131072);
    int*   cnt  = (int*)(ws + 16777216 + 262144);
    int*   pb   = cnt + 16;
    unsigned short* qkh = (unsigned short*)(ws + 33554432);
    unsigned short* qkl = (unsigned short*)(ws + 67108864);
    unsigned short* vth = (unsigned short*)(ws + 100663296);
    unsigned short* vtl = (unsigned short*)(ws + 117440512);
    unsigned short* wt13 = (unsigned short*)(ws + 33554432);
    unsigned short* wt2  = (unsigned short*)(ws + 33554432);
    unsigned short* wqkvh = (unsigned short*)(ws + 134217728);
    unsigned short* wqkvl = (unsigned short*)(ws + 134217728 + 25165824);
    unsigned short* ctxh = (unsigned short*)(ws + 134217728);
    unsigned short* ctxl = (unsigned short*)(ws + 150994944);
    float*          res2 = (float*)(ws + 167772160);
    unsigned short* Hbuf = (unsigned short*)(ws + 167772160);
    float2*         rtab = (float2*)(ws + 201326592);

    rope_tab_k<<<512, 256, 0, stream>>>(rtab);
    rmsnorm_k<<<CT, 256, 0, stream>>>(hidden, rms1w, h1h, h1l);
    convs_k<3><<<dim3(32, 32, 3), 256, 0, stream>>>(qw, kw, vw, wqkvh, wqkvl);
    sgemm_k<0><<<dim3(32, 48), 256, 0, stream>>>(h1h, h1l, CH, wqkvh, wqkvl, CH,
                                                 qkh, qkl, nullptr, CQK, nullptr, nullptr,
                                                 vth, vtl, posids, rtab);
    convs_k<1><<<dim3(32, 32, 1), 256, 0, stream>>>(ow, nullptr, nullptr, woh, wol);
    attn_k<<<1024, 256, 0, stream>>>(qkh, qkl, vth, vtl, ctxh, ctxl);
    sgemm_k<1><<<dim3(32, 16), 256, 0, stream>>>(ctxh, ctxl, CH, woh, wol, CH,
                                                 nullptr, nullptr, res2, CH, hidden, out,
                                                 nullptr, nullptr, nullptr, nullptr);
    hipMemsetAsync(cnt, 0, 8 * sizeof(int), stream);
    rmsrouter_k<<<CT, 256, 0, stream>>>(res2, rms2w, rw, h2, cnt, tok, gate);
    prefix_k<<<1, 64, 0, stream>>>(cnt, pb);
    conv_k<2><<<dim3(32, 32, CE), 256, 0, stream>>>(w1, w3, wt13);
    gemm_k<2><<<dim3(16, 32, CE), 256, 0, stream>>>(h2, CH, wt13, CH, 2 * CI, Hbuf, CI,
                                                    cnt, tok, gate, pb);
    conv_k<1><<<dim3(32, 32, CE), 256, 0, stream>>>(w2, nullptr, wt2);
    gemm_k<3><<<dim3(8, 32, CE), 256, 0, stream>>>(Hbuf, CI, wt2, CI, CH, out, CH,
                                                   cnt, tok, gate, pb);
}

// Round 16
// 1273.535 us; speedup vs baseline: 1.2567x; 1.2567x over previous
//
#include <hip/hip_runtime.h>
#include <hip/hip_bf16.h>

// ---------------- constants ----------------
constexpr int CB   = 2;
constexpr int CS   = 2048;
constexpr int CH   = 2048;
constexpr int CNH  = 16;
constexpr int CHD  = 128;
constexpr int CE   = 8;
constexpr int CI   = 2048;
constexpr int CT   = CB * CS;
constexpr int CQK  = 4096;   // q|k row stride

typedef __attribute__((ext_vector_type(8))) short short8;
typedef __attribute__((ext_vector_type(4))) float float4v;
typedef __attribute__((ext_vector_type(4))) unsigned short ushort4v;
typedef unsigned int uint32;

__device__ __forceinline__ float bf2f(unsigned short u) {
    union { unsigned int i; float f; } x; x.i = ((unsigned int)u) << 16; return x.f;
}
__device__ __forceinline__ unsigned short f2bf(float f) {
    union { float f; unsigned int i; } x; x.f = f;
    unsigned int r = x.i + 0x7fffu + ((x.i >> 16) & 1u);
    return (unsigned short)(r >> 16);
}
__device__ __forceinline__ uint32 packpair(uint32 r0, uint32 r1) {
    return __builtin_amdgcn_perm(r1, r0, 0x07060302u);
}
__device__ __forceinline__ uint32 rnebits(float f) {
    uint32 u = __float_as_uint(f);
    return u + 0x7fffu + ((u >> 16) & 1u);
}
__device__ __forceinline__ void split2(float f0, float f1, uint32& h, uint32& l) {
    uint32 r0 = rnebits(f0), r1 = rnebits(f1);
    h = packpair(r0, r1);
    float d0 = f0 - __uint_as_float(r0 & 0xffff0000u);
    float d1 = f1 - __uint_as_float(r1 & 0xffff0000u);
    l = packpair(rnebits(d0), rnebits(d1));
}
__device__ __forceinline__ void rne16_store(const float* fv, unsigned short* dst) {
    uint32 h[8];
    #pragma unroll
    for (int p = 0; p < 8; p++) h[p] = packpair(rnebits(fv[2 * p]), rnebits(fv[2 * p + 1]));
    ((uint4*)dst)[0] = make_uint4(h[0], h[1], h[2], h[3]);
    ((uint4*)dst)[1] = make_uint4(h[4], h[5], h[6], h[7]);
}
// async global->LDS: 16B per lane, lds dest = wave-uniform base + lane*16
__device__ __forceinline__ void gl16(const void* g, void* l) {
    __builtin_amdgcn_global_load_lds(
        (const __attribute__((address_space(1))) void*)g,
        (__attribute__((address_space(3))) void*)l, 16, 0, 0);
}

// ---------------- RMSNorm (hi/lo split out) ----------
__global__ __launch_bounds__(256) void rmsnorm_k(const float* __restrict__ x,
                                                 const float* __restrict__ w,
                                                 unsigned short* __restrict__ o1,
                                                 unsigned short* __restrict__ o2) {
    const int row = blockIdx.x;
    const float* xr = x + (size_t)row * CH;
    const int base = threadIdx.x * 8;
    float4 v0 = *(const float4*)(xr + base);
    float4 v1 = *(const float4*)(xr + base + 4);
    float ss = v0.x*v0.x + v0.y*v0.y + v0.z*v0.z + v0.w*v0.w
             + v1.x*v1.x + v1.y*v1.y + v1.z*v1.z + v1.w*v1.w;
    #pragma unroll
    for (int o = 1; o < 64; o <<= 1) ss += __shfl_xor(ss, o);
    __shared__ float ps[4];
    if ((threadIdx.x & 63) == 0) ps[threadIdx.x >> 6] = ss;
    __syncthreads();
    const float scale = rsqrtf((ps[0] + ps[1] + ps[2] + ps[3]) / (float)CH + 1e-5f);
    float4 w0 = *(const float4*)(w + base);
    float4 w1 = *(const float4*)(w + base + 4);
    float r[8] = {v0.x * scale * w0.x, v0.y * scale * w0.y, v0.z * scale * w0.z, v0.w * scale * w0.w,
                  v1.x * scale * w1.x, v1.y * scale * w1.y, v1.z * scale * w1.z, v1.w * scale * w1.w};
    uint32 h[4], l[4];
    #pragma unroll
    for (int p = 0; p < 4; p++) split2(r[2 * p], r[2 * p + 1], h[p], l[p]);
    *(uint4*)(o1 + (size_t)row * CH + base) = make_uint4(h[0], h[1], h[2], h[3]);
    *(uint4*)(o2 + (size_t)row * CH + base) = make_uint4(l[0], l[1], l[2], l[3]);
}

// ---------------- fused RMSNorm2 + router ----------------
__global__ __launch_bounds__(256) void rmsrouter_k(const float* __restrict__ x,
                                                   const float* __restrict__ w,
                                                   const float* __restrict__ rw,
                                                   unsigned short* __restrict__ h2,
                                                   int* __restrict__ cnt,
                                                   int* __restrict__ tok,
                                                   float* __restrict__ gate) {
    const int row = blockIdx.x;
    const float* xr = x + (size_t)row * CH;
    const int base = threadIdx.x * 8;
    float4 v0 = *(const float4*)(xr + base);
    float4 v1 = *(const float4*)(xr + base + 4);
    float ss = v0.x*v0.x + v0.y*v0.y + v0.z*v0.z + v0.w*v0.w
             + v1.x*v1.x + v1.y*v1.y + v1.z*v1.z + v1.w*v1.w;
    #pragma unroll
    for (int o = 1; o < 64; o <<= 1) ss += __shfl_xor(ss, o);
    __shared__ float ps[4];
    __shared__ double dacc[4][8];
    const int wave = threadIdx.x >> 6, lane = threadIdx.x & 63;
    if (lane == 0) ps[wave] = ss;
    __syncthreads();
    const float scale = rsqrtf((ps[0] + ps[1] + ps[2] + ps[3]) / (float)CH + 1e-5f);
    float4 w0 = *(const float4*)(w + base);
    float4 w1 = *(const float4*)(w + base + 4);
    float r[8] = {v0.x * scale * w0.x, v0.y * scale * w0.y, v0.z * scale * w0.z, v0.w * scale * w0.w,
                  v1.x * scale * w1.x, v1.y * scale * w1.y, v1.z * scale * w1.z, v1.w * scale * w1.w};
    rne16_store(r, h2 + (size_t)row * CH + base);
    const float vv[8] = {v0.x, v0.y, v0.z, v0.w, v1.x, v1.y, v1.z, v1.w};
    const float ww[8] = {w0.x, w0.y, w0.z, w0.w, w1.x, w1.y, w1.z, w1.w};
    double acc[8] = {0, 0, 0, 0, 0, 0, 0, 0};
    #pragma unroll
    for (int jj = 0; jj < 8; jj++) {
        const double xn = (double)vv[jj] * (double)ww[jj];
        const float* rr = rw + (size_t)(base + jj) * CE;
        #pragma unroll
        for (int e = 0; e < 8; e++) acc[e] += xn * (double)rr[e];
    }
    #pragma unroll
    for (int e = 0; e < 8; e++) {
        #pragma unroll
        for (int o = 1; o < 64; o <<= 1) acc[e] += __shfl_xor(acc[e], o);
    }
    if (lane == 0) {
        #pragma unroll
        for (int e = 0; e < 8; e++) dacc[wave][e] = acc[e];
    }
    __syncthreads();
    if (threadIdx.x == 0) {
        double a[8];
        #pragma unroll
        for (int e = 0; e < 8; e++) a[e] = dacc[0][e] + dacc[1][e] + dacc[2][e] + dacc[3][e];
        int e0 = 0;
        #pragma unroll
        for (int e = 1; e < 8; e++) if (a[e] > a[e0]) e0 = e;
        int e1 = (e0 == 0) ? 1 : 0;
        #pragma unroll
        for (int e = 0; e < 8; e++) if (e != e0 && a[e] > a[e1]) e1 = e;
        const double dl = (double)scale * (a[e1] - a[e0]);   // <= 0
        const double p1r = exp(dl);
        const float g0 = (float)(1.0 / (1.0 + p1r));
        const float g1 = (float)(p1r / (1.0 + p1r));
        int pos0 = atomicAdd(&cnt[e0], 1);
        tok[e0 * 4096 + pos0] = row; gate[e0 * 4096 + pos0] = g0;
        int pos1 = atomicAdd(&cnt[e1], 1);
        tok[e1 * 4096 + pos1] = row; gate[e1 * 4096 + pos1] = g1;
    }
}

// ---------------- RoPE table ----
__global__ void rope_tab_k(float2* __restrict__ tab) {
    int i = blockIdx.x * 256 + threadIdx.x;
    int p = i >> 6, j = i & 63;
    double inv = pow(10000.0, -(double)j / 64.0);
    float invf = (float)inv;
    float angf = (float)p * invf;
    double da = (double)angf;
    tab[i] = make_float2((float)cos(da), (float)sin(da));
}

// ---------------- weight transpose+convert: src[K][N] f32 -> dst[N][K] bf16 ----
template<int NMAT>
__global__ __launch_bounds__(256) void conv_k(const float* __restrict__ S0,
                                              const float* __restrict__ S1,
                                              unsigned short* __restrict__ D) {
    __shared__ float t[64][65];
    const int n0 = blockIdx.x * 64, k0 = blockIdx.y * 64, e = blockIdx.z;
    const size_t esrc = (size_t)e * 2048 * 2048;
    const int cc = threadIdx.x & 63, r4 = threadIdx.x >> 6;
    const int nl = threadIdx.x >> 2, q = threadIdx.x & 3;
    #pragma unroll
    for (int s = 0; s < NMAT; s++) {
        const float* S = s ? S1 : S0;
        __syncthreads();
        #pragma unroll
        for (int j = 0; j < 16; j++) {
            const int row = j * 4 + r4;
            t[cc][row] = S[esrc + (size_t)(k0 + row) * 2048 + n0 + cc];
        }
        __syncthreads();
        const int orow = (NMAT == 2) ? (2 * (n0 + nl) + s) : (n0 + nl);
        unsigned short* dp = D + (size_t)e * (NMAT * 2048) * 2048 + (size_t)orow * 2048 + k0 + q * 16;
        float fv[16];
        #pragma unroll
        for (int j = 0; j < 16; j++) fv[j] = t[nl][q * 16 + j];
        rne16_store(fv, dp);
    }
}

// ---------------- weight transpose + hi/lo SPLIT convert --------------------
// NMAT==3 (q,k,v): z<2 columns get rope-interleaved head-dim: d<64 -> 2d, d>=64 -> 2(d-64)+1
template<int NMAT>
__global__ __launch_bounds__(256) void convs_k(const float* __restrict__ S0,
                                               const float* __restrict__ S1,
                                               const float* __restrict__ S2,
                                               unsigned short* __restrict__ Dh,
                                               unsigned short* __restrict__ Dl) {
    __shared__ float t[64][65];
    const int n0 = blockIdx.x * 64, k0 = blockIdx.y * 64, z = blockIdx.z;
    const float* S = S0;
    if (NMAT == 3) S = (z == 0) ? S0 : ((z == 1) ? S1 : S2);
    const int cc = threadIdx.x & 63, r4 = threadIdx.x >> 6;
    #pragma unroll
    for (int j = 0; j < 16; j++) {
        const int row = j * 4 + r4;
        t[cc][row] = S[(size_t)(k0 + row) * 2048 + n0 + cc];
    }
    __syncthreads();
    const int nl = threadIdx.x >> 2, q = threadIdx.x & 3;
    float fv[16];
    #pragma unroll
    for (int j = 0; j < 16; j++) fv[j] = t[nl][q * 16 + j];
    uint32 h[8], l[8];
    #pragma unroll
    for (int p = 0; p < 8; p++) split2(fv[2 * p], fv[2 * p + 1], h[p], l[p]);
    int orow;
    const int gcol = n0 + nl;
    if (NMAT == 3 && z < 2) {
        const int head = gcol >> 7, dd = gcol & 127;
        const int nd = (dd < 64) ? (2 * dd) : (2 * (dd - 64) + 1);
        orow = z * 2048 + head * 128 + nd;
    } else {
        orow = z * 2048 + gcol;
    }
    const size_t off = (size_t)orow * 2048 + k0 + q * 16;
    ((uint4*)(Dh + off))[0] = make_uint4(h[0], h[1], h[2], h[3]);
    ((uint4*)(Dh + off))[1] = make_uint4(h[4], h[5], h[6], h[7]);
    ((uint4*)(Dl + off))[0] = make_uint4(l[0], l[1], l[2], l[3]);
    ((uint4*)(Dl + off))[1] = make_uint4(l[4], l[5], l[6], l[7]);
}

// ---------------- precise split-bf16 GEMM, gl16 + LDS double-buffer -----------
// MODE 0 (QKV): q,k cols (nt<32) get fused ROPE then split-store (stride 4096);
//               v cols (nt>=32) -> Vh/Vl transposed [vcol][token]
// MODE 1 (O-proj): C f32 + resid, dual-store
template<int MODE>
__global__ __launch_bounds__(256) void sgemm_k(
    const unsigned short* __restrict__ Ahg, const unsigned short* __restrict__ Alg, int lda,
    const unsigned short* __restrict__ Bhg, const unsigned short* __restrict__ Blg, int K,
    unsigned short* __restrict__ Ch, unsigned short* __restrict__ Cl,
    float* __restrict__ Cf, int ldc,
    const float* __restrict__ resid, float* __restrict__ C2,
    unsigned short* __restrict__ Vh, unsigned short* __restrict__ Vl,
    const int* __restrict__ posids, const float2* __restrict__ rtab) {
    __shared__ unsigned short SS[2][4][128 * 32];
    const int mt = blockIdx.x, nt = blockIdx.y, tid = threadIdx.x;
    const int m0 = mt * 128;
    const int wave = tid >> 6, lane = tid & 63;
    const int lr = lane & 15, lg = lane >> 4;
    const int wr = (tid >> 7) & 1, wc = (tid >> 6) & 1;
    const int sr = lane >> 2;
    const int sc = (lane & 3) * 8;
    const int r0 = wave * 32;
    const int lofs = r0 * 32;
    const unsigned short* gAh = Ahg + (size_t)(m0 + r0 + sr) * lda + sc;
    const unsigned short* gAl = Alg + (size_t)(m0 + r0 + sr) * lda + sc;
    const unsigned short* gBh = Bhg + (size_t)(nt * 128 + r0 + sr) * K + sc;
    const unsigned short* gBl = Blg + (size_t)(nt * 128 + r0 + sr) * K + sc;
    const size_t rstepA = (size_t)16 * lda, rstepB = (size_t)16 * K;

    float4v acc[4][4];
    #pragma unroll
    for (int m = 0; m < 4; m++)
        #pragma unroll
        for (int n = 0; n < 4; n++) acc[m][n] = (float4v){0.f, 0.f, 0.f, 0.f};

    gl16(gAh, &SS[0][0][lofs]);           gl16(gAh + rstepA, &SS[0][0][lofs + 512]);
    gl16(gAl, &SS[0][1][lofs]);           gl16(gAl + rstepA, &SS[0][1][lofs + 512]);
    gl16(gBh, &SS[0][2][lofs]);           gl16(gBh + rstepB, &SS[0][2][lofs + 512]);
    gl16(gBl, &SS[0][3][lofs]);           gl16(gBl + rstepB, &SS[0][3][lofs + 512]);
    __syncthreads();

    int cur = 0;
    for (int k0 = 0; k0 < K; k0 += 32) {
        if (k0 + 32 < K) {
            const int nb = cur ^ 1;
            const int kn = k0 + 32;
            gl16(gAh + kn, &SS[nb][0][lofs]);          gl16(gAh + kn + rstepA, &SS[nb][0][lofs + 512]);
            gl16(gAl + kn, &SS[nb][1][lofs]);          gl16(gAl + kn + rstepA, &SS[nb][1][lofs + 512]);
            gl16(gBh + kn, &SS[nb][2][lofs]);          gl16(gBh + kn + rstepB, &SS[nb][2][lofs + 512]);
            gl16(gBl + kn, &SS[nb][3][lofs]);          gl16(gBl + kn + rstepB, &SS[nb][3][lofs + 512]);
        }
        const unsigned short* PAh = SS[cur][0];
        const unsigned short* PAl = SS[cur][1];
        const unsigned short* PBh = SS[cur][2];
        const unsigned short* PBl = SS[cur][3];
        short8 fah[4], fal[4], fbh[4], fbl[4];
        #pragma unroll
        for (int m = 0; m < 4; m++) {
            fah[m] = *(const short8*)(PAh + (wr * 64 + m * 16 + lr) * 32 + lg * 8);
            fal[m] = *(const short8*)(PAl + (wr * 64 + m * 16 + lr) * 32 + lg * 8);
        }
        #pragma unroll
        for (int n = 0; n < 4; n++) {
            fbh[n] = *(const short8*)(PBh + (wc * 64 + n * 16 + lr) * 32 + lg * 8);
            fbl[n] = *(const short8*)(PBl + (wc * 64 + n * 16 + lr) * 32 + lg * 8);
        }
        #pragma unroll
        for (int n = 0; n < 4; n++)
            #pragma unroll
            for (int m = 0; m < 4; m++) {
                acc[m][n] = __builtin_amdgcn_mfma_f32_16x16x32_bf16(fal[m], fbh[n], acc[m][n], 0, 0, 0);
                acc[m][n] = __builtin_amdgcn_mfma_f32_16x16x32_bf16(fah[m], fbl[n], acc[m][n], 0, 0, 0);
                acc[m][n] = __builtin_amdgcn_mfma_f32_16x16x32_bf16(fah[m], fbh[n], acc[m][n], 0, 0, 0);
            }
        __syncthreads();
        cur ^= 1;
    }
    if (MODE == 0 && nt >= 32) {
        // V columns: transposed packed store vT[vcol][token]
        #pragma unroll
        for (int m = 0; m < 4; m++) {
            const int rb = wr * 64 + m * 16 + lg * 4;
            #pragma unroll
            for (int n = 0; n < 4; n++) {
                const int vcol = nt * 128 + wc * 64 + n * 16 + lr - 4096;
                ushort4v wh4, wl4;
                #pragma unroll
                for (int r = 0; r < 4; r++) {
                    const float v = acc[m][n][r];
                    uint32 rr = rnebits(v);
                    wh4[r] = (unsigned short)(rr >> 16);
                    wl4[r] = f2bf(v - __uint_as_float(rr & 0xffff0000u));
                }
                *(ushort4v*)(Vh + (size_t)vcol * (size_t)CT + (m0 + rb)) = wh4;
                *(ushort4v*)(Vl + (size_t)vcol * (size_t)CT + (m0 + rb)) = wl4;
            }
        }
        return;
    }
    if (MODE == 0) {
        // q/k columns: fused rope (interleaved pairs at adjacent lanes) + split store
        #pragma unroll
        for (int m = 0; m < 4; m++) {
            const int rb = wr * 64 + m * 16 + lg * 4;
            #pragma unroll
            for (int n = 0; n < 4; n++) {
                const int ccol = nt * 128 + wc * 64 + n * 16 + lr;
                const int j = (wc * 64 + n * 16 + lr) >> 1;   // head-local pair index
                #pragma unroll
                for (int r = 0; r < 4; r++) {
                    const int row = m0 + rb + r;
                    const float v = acc[m][n][r];
                    const float partner = __shfl_xor(v, 1);
                    const float2 cs = rtab[(size_t)posids[row] * 64 + j];
                    const float y = (lr & 1) ? (v * cs.x + partner * cs.y)
                                             : (v * cs.x - partner * cs.y);
                    const size_t idx = (size_t)row * ldc + ccol;
                    uint32 rr = rnebits(y);
                    Ch[idx] = (unsigned short)(rr >> 16);
                    Cl[idx] = f2bf(y - __uint_as_float(rr & 0xffff0000u));
                }
            }
        }
        return;
    }
    #pragma unroll
    for (int m = 0; m < 4; m++) {
        const int rb = wr * 64 + m * 16 + lg * 4;
        #pragma unroll
        for (int n = 0; n < 4; n++) {
            const int ccol = nt * 128 + wc * 64 + n * 16 + lr;
            #pragma unroll
            for (int r = 0; r < 4; r++) {
                const size_t idx = (size_t)(m0 + rb + r) * ldc + ccol;
                const float v = acc[m][n][r] + resid[idx];
                Cf[idx] = v;
                C2[idx] = v;
            }
        }
    }
}

// ---------------- MoE GEMM, gl16 + LDS double-buffer (round-12 structure) ----
template<int MODE>
__global__ __launch_bounds__(256) void gemm_k(
    const unsigned short* __restrict__ A, int lda,
    const unsigned short* __restrict__ Bt, int K, int Ne,
    void* __restrict__ Cp, int ldc,
    const int* __restrict__ cnt, const int* __restrict__ tokl,
    const float* __restrict__ gatel, const int* __restrict__ pb) {
    __shared__ unsigned short SS[2][2][128 * 32];
    const int nt = blockIdx.x, mt = blockIdx.y, e = blockIdx.z;
    const int m0 = mt * 128;
    const int c = cnt[e];
    if (m0 >= c) return;
    const int valid = (c - m0 < 128) ? (c - m0) : 128;
    const int tid = threadIdx.x;
    const int wave = tid >> 6, lane = tid & 63;
    const int lr = lane & 15;
    const int wr = (tid >> 7) & 1, wc = (tid >> 6) & 1;
    const int sr = lane >> 2, sc = (lane & 3) * 8;
    const int r0 = wave * 32;
    const int lofs = r0 * 32;
    size_t gr0, gr1;
    {
        int ra = r0 + sr, rb2 = r0 + 16 + sr;
        if (MODE == 2) {
            ra = ra < valid ? ra : valid - 1;
            rb2 = rb2 < valid ? rb2 : valid - 1;
            gr0 = (size_t)tokl[e * 4096 + m0 + ra];
            gr1 = (size_t)tokl[e * 4096 + m0 + rb2];
        } else {
            int x0 = m0 + ra, x1 = m0 + rb2;
            gr0 = (size_t)(pb[e] + (x0 < c ? x0 : c - 1));
            gr1 = (size_t)(pb[e] + (x1 < c ? x1 : c - 1));
        }
    }
    const unsigned short* gA0 = A + gr0 * (size_t)lda + sc;
    const unsigned short* gA1 = A + gr1 * (size_t)lda + sc;
    const unsigned short* gB = Bt + (size_t)e * Ne * K + (size_t)(nt * 128 + r0 + sr) * K + sc;
    const size_t rstepB = (size_t)16 * K;

    float4v acc[4][4];
    #pragma unroll
    for (int m = 0; m < 4; m++)
        #pragma unroll
        for (int n = 0; n < 4; n++) acc[m][n] = (float4v){0.f, 0.f, 0.f, 0.f};

    gl16(gA0, &SS[0][0][lofs]);           gl16(gA1, &SS[0][0][lofs + 512]);
    gl16(gB, &SS[0][1][lofs]);            gl16(gB + rstepB, &SS[0][1][lofs + 512]);
    __syncthreads();

    int cur = 0;
    for (int k0 = 0; k0 < K; k0 += 32) {
        if (k0 + 32 < K) {
            const int nb = cur ^ 1;
            const int kn = k0 + 32;
            gl16(gA0 + kn, &SS[nb][0][lofs]);          gl16(gA1 + kn, &SS[nb][0][lofs + 512]);
            gl16(gB + kn, &SS[nb][1][lofs]);           gl16(gB + kn + rstepB, &SS[nb][1][lofs + 512]);
        }
        const unsigned short* PA = SS[cur][0];
        const unsigned short* PB = SS[cur][1];
        short8 af[4], bf[4];
        const int lg = lane >> 4;
        #pragma unroll
        for (int m = 0; m < 4; m++) af[m] = *(const short8*)(PA + (wr * 64 + m * 16 + lr) * 32 + lg * 8);
        #pragma unroll
        for (int n = 0; n < 4; n++) bf[n] = *(const short8*)(PB + (wc * 64 + n * 16 + lr) * 32 + lg * 8);
        #pragma unroll
        for (int n = 0; n < 4; n++)
            #pragma unroll
            for (int m = 0; m < 4; m++)
                acc[m][n] = __builtin_amdgcn_mfma_f32_16x16x32_bf16(af[m], bf[n], acc[m][n], 0, 0, 0);
        __syncthreads();
        cur ^= 1;
    }

    #pragma unroll
    for (int m = 0; m < 4; m++) {
        const int rb = wr * 64 + m * 16 + (lane >> 4) * 4;
        #pragma unroll
        for (int n = 0; n < 4; n++) {
            const int col = nt * 128 + wc * 64 + n * 16 + lr;
            #pragma unroll
            for (int r = 0; r < 4; r++) {
                const int row = rb + r;
                const float v = acc[m][n][r];
                if (MODE == 2) {
                    const float other = __shfl_xor(v, 1);
                    if (!(lr & 1) && row < valid) {
                        const float g1 = v, g3 = other;
                        const float hsw = (g1 / (1.f + __expf(-g1))) * g3;
                        ((unsigned short*)Cp)[(size_t)(pb[e] + m0 + row) * ldc + (col >> 1)] = f2bf(hsw);
                    }
                } else {
                    if (row < valid) {
                        const int t = tokl[e * 4096 + m0 + row];
                        const float g = gatel[e * 4096 + m0 + row];
                        atomicAdd(((float*)Cp) + (size_t)t * ldc + col, v * g);
                    }
                }
            }
        }
    }
}

// ---------------- flash attention: XCD-pinned, single-barrier dbuf, gl16 V ----
__global__ __launch_bounds__(256) void attn_k(const unsigned short* __restrict__ qkh,
                                              const unsigned short* __restrict__ qkl,
                                              const unsigned short* __restrict__ vth,
                                              const unsigned short* __restrict__ vtl,
                                              unsigned short* __restrict__ ch,
                                              unsigned short* __restrict__ cl) {
    __shared__ unsigned short Kb[2][2][32][136];
    __shared__ unsigned short Vb[2][2][128 * 32];
    const int bid = blockIdx.x;          // 1024 blocks
    const int xcd = bid & 7, jj = bid >> 3;
    const int bh  = xcd * 4 + (jj >> 5);
    const int qb  = 31 - (jj & 31);
    const int h   = bh & 15, b = bh >> 4;
    const int tid = threadIdx.x;
    const int wave = tid >> 6, lane = tid & 63, lr = lane & 15, lg = lane >> 4;
    const size_t tb = (size_t)b * CS;
    const int q0 = qb * 64 + wave * 16;

    short8 qfh[4], qfl[4];
    {
        const size_t off = (tb + q0 + lr) * CQK + h * CHD;
        #pragma unroll
        for (int c = 0; c < 4; c++) {
            qfh[c] = *(const short8*)(qkh + off + c * 32 + lg * 8);
            qfl[c] = *(const short8*)(qkl + off + c * 32 + lg * 8);
        }
    }
    float4v o[8];
    #pragma unroll
    for (int d = 0; d < 8; d++) o[d] = (float4v){0.f, 0.f, 0.f, 0.f};
    float m = -1e30f, l = 0.f;
    const float scl = 0.08838834764831845f;
    const int ntiles = 2 * (qb + 1);
    const int kk = tid >> 3, slot = tid & 7;

    short8 kh0, kh1, kl0, kl1;
    const size_t vrow = (size_t)(h * 128 + wave * 32 + (lane >> 2));
    const unsigned short* gV0 = vth + vrow * (size_t)CT + tb + (lane & 3) * 8;
    const unsigned short* gV1 = vtl + vrow * (size_t)CT + tb + (lane & 3) * 8;

    #define LOADK(KV0) { \
        const size_t koff = (tb + (KV0) + kk) * CQK + CH + h * CHD + slot * 16; \
        kh0 = *(const short8*)(qkh + koff);     kh1 = *(const short8*)(qkh + koff + 8); \
        kl0 = *(const short8*)(qkl + koff);     kl1 = *(const short8*)(qkl + koff + 8); }
    #define WRITEK(BUF) { \
        *(short8*)(&Kb[BUF][0][kk][slot * 16])     = kh0; \
        *(short8*)(&Kb[BUF][0][kk][slot * 16 + 8]) = kh1; \
        *(short8*)(&Kb[BUF][1][kk][slot * 16])     = kl0; \
        *(short8*)(&Kb[BUF][1][kk][slot * 16 + 8]) = kl1; }
    #define ISSUEV(BUF, KV0) { \
        gl16(gV0 + (KV0), &Vb[BUF][0][wave * 32 * 32]); \
        gl16(gV0 + (KV0) + (size_t)16 * CT, &Vb[BUF][0][wave * 32 * 32 + 512]); \
        gl16(gV1 + (KV0), &Vb[BUF][1][wave * 32 * 32]); \
        gl16(gV1 + (KV0) + (size_t)16 * CT, &Vb[BUF][1][wave * 32 * 32 + 512]); }

    LOADK(0);
    WRITEK(0);
    ISSUEV(0, 0);
    LOADK(32);
    __syncthreads();

    int cur = 0;
    for (int kt = 0; kt < ntiles; ++kt) {
        const int kv0 = kt * 32;
        if (kt + 1 < ntiles) {
            WRITEK(cur ^ 1);
            ISSUEV(cur ^ 1, kv0 + 32);
        }
        if (kt + 2 < ntiles) LOADK(kv0 + 64);

        const unsigned short* KH = &Kb[cur][0][0][0];
        const unsigned short* KL = &Kb[cur][1][0][0];
        const unsigned short* VH = Vb[cur][0];
        const unsigned short* VL = Vb[cur][1];

        float4v st0 = (float4v){0.f,0.f,0.f,0.f}, st1 = st0;
        #pragma unroll
        for (int c = 0; c < 4; c++) {
            short8 kah = *(const short8*)(KH + lr * 136 + c * 32 + lg * 8);
            short8 kal = *(const short8*)(KL + lr * 136 + c * 32 + lg * 8);
            short8 kbh = *(const short8*)(KH + (16 + lr) * 136 + c * 32 + lg * 8);
            short8 kbl = *(const short8*)(KL + (16 + lr) * 136 + c * 32 + lg * 8);
            st0 = __builtin_amdgcn_mfma_f32_16x16x32_bf16(kal, qfh[c], st0, 0, 0, 0);
            st0 = __builtin_amdgcn_mfma_f32_16x16x32_bf16(kah, qfl[c], st0, 0, 0, 0);
            st0 = __builtin_amdgcn_mfma_f32_16x16x32_bf16(kah, qfh[c], st0, 0, 0, 0);
            st1 = __builtin_amdgcn_mfma_f32_16x16x32_bf16(kbl, qfh[c], st1, 0, 0, 0);
            st1 = __builtin_amdgcn_mfma_f32_16x16x32_bf16(kbh, qfl[c], st1, 0, 0, 0);
            st1 = __builtin_amdgcn_mfma_f32_16x16x32_bf16(kbh, qfh[c], st1, 0, 0, 0);
        }
        float pv[8]; float pmax = -1e30f;
        const int qg = q0 + lr;
        #pragma unroll
        for (int f = 0; f < 2; f++) {
            #pragma unroll
            for (int r = 0; r < 4; r++) {
                const int kg = kv0 + f * 16 + lg * 4 + r;
                const float s = (kg <= qg) ? ((f ? st1[r] : st0[r]) * scl) : -1e30f;
                pv[f * 4 + r] = s;
                pmax = fmaxf(pmax, s);
            }
        }
        pmax = fmaxf(pmax, __shfl_xor(pmax, 16));
        pmax = fmaxf(pmax, __shfl_xor(pmax, 32));
        if (!__all(pmax <= m)) {
            const float mnew = fmaxf(m, pmax);
            const float alpha = __expf(m - mnew);
            l *= alpha;
            #pragma unroll
            for (int d = 0; d < 8; d++) o[d] *= alpha;
            m = mnew;
        }
        float sum = 0.f;
        #pragma unroll
        for (int i = 0; i < 8; i++) { const float p = __expf(pv[i] - m); pv[i] = p; sum += p; }
        sum += __shfl_xor(sum, 16);
        sum += __shfl_xor(sum, 32);
        l += sum;
        short8 pfh, pfl;
        unsigned short* pfhp = (unsigned short*)&pfh;
        unsigned short* pflp = (unsigned short*)&pfl;
        #pragma unroll
        for (int j = 0; j < 8; j++) {
            const int srcl = (((lg & 1) * 2 + (j >> 2)) << 4) | lr;
            const float a0 = __shfl(pv[j & 3], srcl);
            const float a1 = __shfl(pv[4 + (j & 3)], srcl);
            const float sel = (lg >= 2) ? a1 : a0;
            uint32 r = rnebits(sel);
            pfhp[j] = (unsigned short)(r >> 16);
            float d = sel - __uint_as_float(r & 0xffff0000u);
            pflp[j] = (unsigned short)(rnebits(d) >> 16);
        }
        #pragma unroll
        for (int dt = 0; dt < 8; dt++) {
            short8 vh = *(const short8*)(VH + (dt * 16 + lr) * 32 + lg * 8);
            short8 vl = *(const short8*)(VL + (dt * 16 + lr) * 32 + lg * 8);
            o[dt] = __builtin_amdgcn_mfma_f32_16x16x32_bf16(vl, pfh, o[dt], 0, 0, 0);
            o[dt] = __builtin_amdgcn_mfma_f32_16x16x32_bf16(vh, pfl, o[dt], 0, 0, 0);
            o[dt] = __builtin_amdgcn_mfma_f32_16x16x32_bf16(vh, pfh, o[dt], 0, 0, 0);
        }
        __syncthreads();
        cur ^= 1;
    }
    #undef LOADK
    #undef WRITEK
    #undef ISSUEV
    const float inv = 1.f / l;
    const size_t coff = (tb + q0 + lr) * CH + h * CHD + lg * 4;
    #pragma unroll
    for (int dt = 0; dt < 8; dt++) {
        ushort4v wh, wl;
        #pragma unroll
        for (int r = 0; r < 4; r++) {
            const float v = o[dt][r] * inv;
            uint32 rr = rnebits(v);
            wh[r] = (unsigned short)(rr >> 16);
            wl[r] = f2bf(v - __uint_as_float(rr & 0xffff0000u));
        }
        *(ushort4v*)(ch + coff + dt * 16) = wh;
        *(ushort4v*)(cl + coff + dt * 16) = wl;
    }
}

__global__ void prefix_k(const int* __restrict__ cnt, int* __restrict__ pb) {
    if (threadIdx.x == 0 && blockIdx.x == 0) {
        int s = 0;
        for (int e = 0; e < CE; e++) { pb[e] = s; s += cnt[e]; }
    }
}

// ---------------- launch ----------------
extern "C" void kernel_launch(void* const* d_in, const int* in_sizes, int n_in,
                              void* d_out, int out_size, void* d_ws, size_t ws_size,
                              hipStream_t stream) {
    (void)in_sizes; (void)n_in; (void)out_size; (void)ws_size;
    const float* hidden = (const float*)d_in[0];
    const int*   posids = (const int*)d_in[1];
    const float* rms1w  = (const float*)d_in[2];
    const float* rms2w  = (const float*)d_in[3];
    const float* qw     = (const float*)d_in[4];
    const float* kw     = (const float*)d_in[5];
    const float* vw     = (const float*)d_in[6];
    const float* ow     = (const float*)d_in[7];
    const float* rw     = (const float*)d_in[8];
    const float* w1     = (const float*)d_in[9];
    const float* w2     = (const float*)d_in[10];
    const float* w3     = (const float*)d_in[11];
    float* out = (float*)d_out;

    char* ws = (char*)d_ws;
    unsigned short* h1h = (unsigned short*)ws;
    unsigned short* h1l = (unsigned short*)(ws + 16777216);
    unsigned short* woh = (unsigned short*)ws;
    unsigned short* wol = (unsigned short*)(ws + 8388608);
    unsigned short* h2  = (unsigned short*)ws;
    int*   tok  = (int*)(ws + 16777216);
    float* gate = (float*)(ws + 16777216 + 131072);
    int*   cnt  = (int*)(ws + 16777216 + 262144);
    int*   pb   = cnt + 16;
    unsigned short* qkh = (unsigned short*)(ws + 33554432);
    unsigned short* qkl = (unsigned short*)(ws + 67108864);
    unsigned short* vth = (unsigned short*)(ws + 100663296);
    unsigned short* vtl = (unsigned short*)(ws + 117440512);
    unsigned short* wt13 = (unsigned short*)(ws + 33554432);
    unsigned short* wt2  = (unsigned short*)(ws + 33554432);
    unsigned short* wqkvh = (unsigned short*)(ws + 134217728);
    unsigned short* wqkvl = (unsigned short*)(ws + 134217728 + 25165824);
    unsigned short* ctxh = (unsigned short*)(ws + 134217728);
    unsigned short* ctxl = (unsigned short*)(ws + 150994944);
    float*          res2 = (float*)(ws + 167772160);
    unsigned short* Hbuf = (unsigned short*)(ws + 167772160);
    float2*         rtab = (float2*)(ws + 201326592);

    rope_tab_k<<<512, 256, 0, stream>>>(rtab);
    rmsnorm_k<<<CT, 256, 0, stream>>>(hidden, rms1w, h1h, h1l);
    convs_k<3><<<dim3(32, 32, 3), 256, 0, stream>>>(qw, kw, vw, wqkvh, wqkvl);
    sgemm_k<0><<<dim3(32, 48), 256, 0, stream>>>(h1h, h1l, CH, wqkvh, wqkvl, CH,
                                                 qkh, qkl, nullptr, CQK, nullptr, nullptr,
                                                 vth, vtl, posids, rtab);
    convs_k<1><<<dim3(32, 32, 1), 256, 0, stream>>>(ow, nullptr, nullptr, woh, wol);
    attn_k<<<1024, 256, 0, stream>>>(qkh, qkl, vth, vtl, ctxh, ctxl);
    sgemm_k<1><<<dim3(32, 16), 256, 0, stream>>>(ctxh, ctxl, CH, woh, wol, CH,
                                                 nullptr, nullptr, res2, CH, hidden, out,
                                                 nullptr, nullptr, nullptr, nullptr);
    hipMemsetAsync(cnt, 0, 8 * sizeof(int), stream);
    rmsrouter_k<<<CT, 256, 0, stream>>>(res2, rms2w, rw, h2, cnt, tok, gate);
    prefix_k<<<1, 64, 0, stream>>>(cnt, pb);
    conv_k<2><<<dim3(32, 32, CE), 256, 0, stream>>>(w1, w3, wt13);
    gemm_k<2><<<dim3(32, 32, CE), 256, 0, stream>>>(h2, CH, wt13, CH, 2 * CI, Hbuf, CI,
                                                    cnt, tok, gate, pb);
    conv_k<1><<<dim3(32, 32, CE), 256, 0, stream>>>(w2, nullptr, wt2);
    gemm_k<3><<<dim3(16, 32, CE), 256, 0, stream>>>(Hbuf, CI, wt2, CI, CH, out, CH,
                                                    cnt, tok, gate, pb);
}